// Round 13
// baseline (119.812 us; speedup 1.0000x reference)
//
#include <hip/hip_runtime.h>
#include <stdint.h>

// ---------------------------------------------------------------------------
// Problem constants (from reference)
// ---------------------------------------------------------------------------
#define EMB   256
#define HEADS 8
#define KMIX  8
#define GADD  2
#define RADD  2
#define REGION 64
#define STRIDE 32
#define BB    4
#define TT    4096
#define TP    128
#define VS    48
#define HID   1024
#define NQ    2048

// ---------------------------------------------------------------------------
// Threefry-2x32 (JAX exact, partitionable mode)
// ---------------------------------------------------------------------------
__device__ __forceinline__ uint32_t rotl32(uint32_t x, int d) {
  return (x << d) | (x >> (32 - d));
}
__device__ __forceinline__ void tf2x32(uint32_t k0, uint32_t k1,
                                       uint32_t x0, uint32_t x1,
                                       uint32_t& o0, uint32_t& o1) {
  uint32_t ks2 = k0 ^ k1 ^ 0x1BD11BDAu;
  x0 += k0; x1 += k1;
#define TFR(r) { x0 += x1; x1 = rotl32(x1, r); x1 ^= x0; }
  TFR(13) TFR(15) TFR(26) TFR(6)
  x0 += k1; x1 += ks2 + 1u;
  TFR(17) TFR(29) TFR(16) TFR(24)
  x0 += ks2; x1 += k0 + 2u;
  TFR(13) TFR(15) TFR(26) TFR(6)
  x0 += k0; x1 += k1 + 3u;
  TFR(17) TFR(29) TFR(16) TFR(24)
  x0 += k1; x1 += ks2 + 4u;
  TFR(13) TFR(15) TFR(26) TFR(6)
  x0 += ks2; x1 += k0 + 5u;
#undef TFR
  o0 = x0; o1 = x1;
}

// sel-row mapping: logical row m (0..511) -> x row index (b*TT + t)
__device__ __forceinline__ size_t selrow(int m) {
  return (size_t)(m >> 7) * TT + ((m & 127) * STRIDE + STRIDE - 1);
}

// ---------------------------------------------------------------------------
// mega1: flat grid, 4864 blocks.
//   bid <  512 : wpre  (zz<8: M8_h = Wq_h Wk_h^T / 16, NT; else PV_h = Wv_h Wu_h, NN)
//   512..767   : MLP hidden = x[sel] @ W1
//   768..4863  : fill out with bu (background; sel rows overwritten later)
// ---------------------------------------------------------------------------
__global__ __launch_bounds__(256) void mega1_kernel(
    const float* __restrict__ Wq, const float* __restrict__ Wk,
    const float* __restrict__ Wv, const float* __restrict__ Wu,
    const float* __restrict__ x,  const float* __restrict__ W1,
    const float* __restrict__ bu,
    float* __restrict__ M8, float* __restrict__ PV, float* __restrict__ hid0,
    float* __restrict__ out)
{
  const int bid = blockIdx.x;
  const int tid = threadIdx.x;

  if (bid >= 768) {
    int i4 = (bid - 768) * 256 + tid;
    ((float4*)out)[i4] = ((const float4*)bu)[i4 & 63];
    return;
  }

  const int tx = tid & 15, ty = tid >> 4;
  __shared__ float As[32][33];
  __shared__ __align__(16) float Braw[64 * 33];

  float acc[2][4];
#pragma unroll
  for (int i = 0; i < 2; i++)
#pragma unroll
    for (int j = 0; j < 4; j++) acc[i][j] = 0.0f;

  if (bid < 512) {
    const int zz = bid >> 5, rem = bid & 31;
    const int n0 = (rem & 3) * 64, m0 = (rem >> 2) * 32;
    if (zz < HEADS) {
      // NT: A = Wq_h (lda NQ), B = Wk_h (ldb NQ), C = M8_h, scale 1/16
      const float* A = Wq + zz * 256;
      const float* B = Wk + zz * 256;
      float* C = M8 + (size_t)zz * EMB * EMB;
      for (int k0 = 0; k0 < EMB; k0 += 32) {
        {
          int r = tid >> 3, kq = tid & 7;
          float4 v = *(const float4*)(A + (size_t)(m0 + r) * NQ + k0 + kq * 4);
          As[r][kq * 4 + 0] = v.x; As[r][kq * 4 + 1] = v.y;
          As[r][kq * 4 + 2] = v.z; As[r][kq * 4 + 3] = v.w;
        }
#pragma unroll
        for (int rr = 0; rr < 2; rr++) {
          int c = tid * 2 + rr;
          int r = c >> 3, kq = c & 7;
          float4 v = *(const float4*)(B + (size_t)(n0 + r) * NQ + k0 + kq * 4);
          Braw[r * 33 + kq * 4 + 0] = v.x; Braw[r * 33 + kq * 4 + 1] = v.y;
          Braw[r * 33 + kq * 4 + 2] = v.z; Braw[r * 33 + kq * 4 + 3] = v.w;
        }
        __syncthreads();
#pragma unroll
        for (int kk = 0; kk < 32; kk++) {
          float a0 = As[ty * 2 + 0][kk], a1 = As[ty * 2 + 1][kk];
          float b0 = Braw[(tx * 4 + 0) * 33 + kk];
          float b1 = Braw[(tx * 4 + 1) * 33 + kk];
          float b2 = Braw[(tx * 4 + 2) * 33 + kk];
          float b3 = Braw[(tx * 4 + 3) * 33 + kk];
          acc[0][0] = fmaf(a0, b0, acc[0][0]); acc[0][1] = fmaf(a0, b1, acc[0][1]);
          acc[0][2] = fmaf(a0, b2, acc[0][2]); acc[0][3] = fmaf(a0, b3, acc[0][3]);
          acc[1][0] = fmaf(a1, b0, acc[1][0]); acc[1][1] = fmaf(a1, b1, acc[1][1]);
          acc[1][2] = fmaf(a1, b2, acc[1][2]); acc[1][3] = fmaf(a1, b3, acc[1][3]);
        }
        __syncthreads();
      }
#pragma unroll
      for (int i = 0; i < 2; i++) {
        float* cp = C + (size_t)(m0 + ty * 2 + i) * EMB + n0 + tx * 4;
        *(float4*)cp = make_float4(acc[i][0] * 0.0625f, acc[i][1] * 0.0625f,
                                   acc[i][2] * 0.0625f, acc[i][3] * 0.0625f);
      }
    } else {
      // NN: A = Wv_h (lda NQ), W = Wu_h (ldw EMB), C = PV_h
      const int hh = zz - HEADS;
      const float* A = Wv + hh * 256;
      const float* W = Wu + (size_t)hh * 256 * EMB;
      float* C = PV + (size_t)hh * EMB * EMB;
      for (int k0 = 0; k0 < EMB; k0 += 32) {
        {
          int r = tid >> 3, kq = tid & 7;
          float4 v = *(const float4*)(A + (size_t)(m0 + r) * NQ + k0 + kq * 4);
          As[r][kq * 4 + 0] = v.x; As[r][kq * 4 + 1] = v.y;
          As[r][kq * 4 + 2] = v.z; As[r][kq * 4 + 3] = v.w;
        }
#pragma unroll
        for (int rr = 0; rr < 2; rr++) {
          int c = tid * 2 + rr;
          int kk = c >> 4, n4 = c & 15;
          *(float4*)(&Braw[kk * 64 + n4 * 4]) =
              *(const float4*)(W + (size_t)(k0 + kk) * EMB + n0 + n4 * 4);
        }
        __syncthreads();
#pragma unroll
        for (int kk = 0; kk < 32; kk++) {
          float a0 = As[ty * 2 + 0][kk], a1 = As[ty * 2 + 1][kk];
          float4 b4 = *(const float4*)&Braw[kk * 64 + tx * 4];
          acc[0][0] = fmaf(a0, b4.x, acc[0][0]); acc[0][1] = fmaf(a0, b4.y, acc[0][1]);
          acc[0][2] = fmaf(a0, b4.z, acc[0][2]); acc[0][3] = fmaf(a0, b4.w, acc[0][3]);
          acc[1][0] = fmaf(a1, b4.x, acc[1][0]); acc[1][1] = fmaf(a1, b4.y, acc[1][1]);
          acc[1][2] = fmaf(a1, b4.z, acc[1][2]); acc[1][3] = fmaf(a1, b4.w, acc[1][3]);
        }
        __syncthreads();
      }
#pragma unroll
      for (int i = 0; i < 2; i++) {
        float* cp = C + (size_t)(m0 + ty * 2 + i) * EMB + n0 + tx * 4;
        *(float4*)cp = make_float4(acc[i][0], acc[i][1], acc[i][2], acc[i][3]);
      }
    }
  } else {
    // MLP hidden: A = sel rows of x, W = W1 (ldw HID), C = hid0
    const int idx = bid - 512;
    const int n0 = (idx & 15) * 64, m0 = (idx >> 4) * 32;
    for (int k0 = 0; k0 < EMB; k0 += 32) {
      {
        int r = tid >> 3, kq = tid & 7;
        float4 v = *(const float4*)(x + selrow(m0 + r) * EMB + k0 + kq * 4);
        As[r][kq * 4 + 0] = v.x; As[r][kq * 4 + 1] = v.y;
        As[r][kq * 4 + 2] = v.z; As[r][kq * 4 + 3] = v.w;
      }
#pragma unroll
      for (int rr = 0; rr < 2; rr++) {
        int c = tid * 2 + rr;
        int kk = c >> 4, n4 = c & 15;
        *(float4*)(&Braw[kk * 64 + n4 * 4]) =
            *(const float4*)(W1 + (size_t)(k0 + kk) * HID + n0 + n4 * 4);
      }
      __syncthreads();
#pragma unroll
      for (int kk = 0; kk < 32; kk++) {
        float a0 = As[ty * 2 + 0][kk], a1 = As[ty * 2 + 1][kk];
        float4 b4 = *(const float4*)&Braw[kk * 64 + tx * 4];
        acc[0][0] = fmaf(a0, b4.x, acc[0][0]); acc[0][1] = fmaf(a0, b4.y, acc[0][1]);
        acc[0][2] = fmaf(a0, b4.z, acc[0][2]); acc[0][3] = fmaf(a0, b4.w, acc[0][3]);
        acc[1][0] = fmaf(a1, b4.x, acc[1][0]); acc[1][1] = fmaf(a1, b4.y, acc[1][1]);
        acc[1][2] = fmaf(a1, b4.z, acc[1][2]); acc[1][3] = fmaf(a1, b4.w, acc[1][3]);
      }
      __syncthreads();
    }
#pragma unroll
    for (int i = 0; i < 2; i++) {
      float* cp = hid0 + (size_t)(m0 + ty * 2 + i) * HID + n0 + tx * 4;
      *(float4*)cp = make_float4(acc[i][0], acc[i][1], acc[i][2], acc[i][3]);
    }
  }
}

// ---------------------------------------------------------------------------
__device__ __forceinline__ float softplus_f(float v) {
  return fmaxf(v, 0.0f) + log1pf(expf(-fabsf(v)));
}

// ---------------------------------------------------------------------------
// phase2: flat grid. bid<512: qk GEMM (qk_h = x[sel] @ M_h).
// bid>=512: params (MLP finish + indices/weights, inline RNG).
// ---------------------------------------------------------------------------
__global__ __launch_bounds__(256) void phase2_kernel(
    const float* __restrict__ x,  const float* __restrict__ M8,
    const float* __restrict__ hid0,
    const float* __restrict__ W1, const float* __restrict__ b1,
    const float* __restrict__ W2, const float* __restrict__ b2,
    float* __restrict__ qk, int* __restrict__ idx_out, float* __restrict__ w_out)
{
  const int bid = blockIdx.x;
  const int tid = threadIdx.x;

  if (bid < 512) {
    const int h = bid >> 6, rem = bid & 63;
    const int n0 = (rem & 3) * 64, m0 = (rem >> 2) * 32;
    const int tx = tid & 15, ty = tid >> 4;
    const float* W = M8 + (size_t)h * EMB * EMB;

    __shared__ float As[32][33];
    __shared__ __align__(16) float Bs[32][64];

    float acc[2][4];
#pragma unroll
    for (int i = 0; i < 2; i++)
#pragma unroll
      for (int j = 0; j < 4; j++) acc[i][j] = 0.0f;

    for (int k0 = 0; k0 < EMB; k0 += 32) {
      {
        int r = tid >> 3, kq = tid & 7;
        float4 v = *(const float4*)(x + selrow(m0 + r) * EMB + k0 + kq * 4);
        As[r][kq * 4 + 0] = v.x; As[r][kq * 4 + 1] = v.y;
        As[r][kq * 4 + 2] = v.z; As[r][kq * 4 + 3] = v.w;
      }
#pragma unroll
      for (int rr = 0; rr < 2; rr++) {
        int c = tid * 2 + rr;
        int kk = c >> 4, n4 = c & 15;
        *(float4*)(&Bs[kk][n4 * 4]) =
            *(const float4*)(W + (size_t)(k0 + kk) * EMB + n0 + n4 * 4);
      }
      __syncthreads();
#pragma unroll
      for (int kk = 0; kk < 32; kk++) {
        float a0 = As[ty * 2 + 0][kk], a1 = As[ty * 2 + 1][kk];
        float4 b4 = *(const float4*)&Bs[kk][tx * 4];
        acc[0][0] = fmaf(a0, b4.x, acc[0][0]); acc[0][1] = fmaf(a0, b4.y, acc[0][1]);
        acc[0][2] = fmaf(a0, b4.z, acc[0][2]); acc[0][3] = fmaf(a0, b4.w, acc[0][3]);
        acc[1][0] = fmaf(a1, b4.x, acc[1][0]); acc[1][1] = fmaf(a1, b4.y, acc[1][1]);
        acc[1][2] = fmaf(a1, b4.z, acc[1][2]); acc[1][3] = fmaf(a1, b4.w, acc[1][3]);
      }
      __syncthreads();
    }
#pragma unroll
    for (int i = 0; i < 2; i++) {
      float* cp = qk + (size_t)(m0 + ty * 2 + i) * NQ + h * 256 + n0 + tx * 4;
      *(float4*)cp = make_float4(acc[i][0], acc[i][1], acc[i][2], acc[i][3]);
    }
  } else {
    const int bp = bid - 512;
    const int b = bp >> 7, p = bp & 127;
    const int selp = STRIDE * p + STRIDE - 1;
    const float coordp = (float)p / (float)TP;
    (void)b;

    __shared__ float shid[HID];
    __shared__ float spartial[256];
    __shared__ float spar[2 * KMIX];
    __shared__ float sm[KMIX], ss[KMIX];
    __shared__ int   sidx[VS];
    __shared__ float sidxf[VS];
    __shared__ int   svalid[VS];
    __shared__ float sprops[KMIX][VS];
    __shared__ float sden[KMIX];
    __shared__ int   sgrand[16], srrand[16];

    if (tid < 16) {
      uint32_t i = (uint32_t)(bp * 16 + tid);
      uint32_t kg0, kg1, kr0, kr1, g2k0, g2k1, r2k0, r2k1, o0, o1;
      tf2x32(0u, 42u, 0u, 0u, kg0, kg1);
      tf2x32(0u, 42u, 0u, 1u, kr0, kr1);
      tf2x32(kg0, kg1, 0u, 1u, g2k0, g2k1);
      tf2x32(kr0, kr1, 0u, 1u, r2k0, r2k1);
      tf2x32(g2k0, g2k1, 0u, i, o0, o1);
      sgrand[tid] = (int)((o0 ^ o1) & 4095u);
      tf2x32(r2k0, r2k1, 0u, i, o0, o1);
      srrand[tid] = (int)((o0 ^ o1) & 63u);
    }

#pragma unroll
    for (int q = 0; q < HID / 256; q++) {
      int j = q * 256 + tid;
      shid[j] = fmaxf(hid0[(size_t)bp * HID + j] + coordp * W1[(size_t)EMB * HID + j] + b1[j], 0.0f);
    }
    __syncthreads();

    {
      int o = tid & 15, g = tid >> 4;
      float pa = 0.0f;
      for (int jj = 0; jj < 64; jj++) {
        int j = g * 64 + jj;
        pa = fmaf(shid[j], W2[j * (2 * KMIX) + o], pa);
      }
      spartial[o * 16 + g] = pa;
    }
    __syncthreads();
    if (tid < 2 * KMIX) {
      float acc = 0.0f;
      for (int g = 0; g < 16; g++) acc += spartial[tid * 16 + g];
      spar[tid] = acc + b2[tid];
    }
    __syncthreads();

    if (tid < KMIX) {
      float m = (float)selp - 3.0f * softplus_f(spar[tid]);
      m = fminf(fmaxf(m, 0.0f), (float)(TT - 1));
      sm[tid] = m;
      ss[tid] = (softplus_f(spar[KMIX + tid] + 2.0f) + 0.05f) * (float)TT * 0.1f;
    }
    __syncthreads();

    if (tid < VS) {
      int kk = tid / 6, jj = tid % 6;
      float fl = floorf(sm[kk]);
      float v;
      if (jj == 0) v = fl;
      else if (jj == 1) v = fl + 1.0f;
      else if (jj < 4) v = (float)sgrand[kk * GADD + (jj - 2)];
      else {
        float lo = fminf(fmaxf(fl - (float)(REGION / 2), 0.0f), (float)(TT - REGION));
        v = lo + (float)srrand[kk * RADD + (jj - 4)];
      }
      v = fminf(fmaxf(v, 0.0f), (float)(TT - 1));
      int ii = (int)v;
      sidx[tid] = ii;
      sidxf[tid] = (float)ii;
    }
    __syncthreads();

    if (tid < VS) {
      int d = 0;
      for (int u = 0; u < tid; u++) d |= (sidx[u] == sidx[tid]);
      svalid[tid] = (!d) && (sidx[tid] <= selp);
    }
    __syncthreads();

    for (int l = tid; l < KMIX * VS; l += 256) {
      int kk = l / VS, v = l - kk * VS;
      float zz = (sidxf[v] - sm[kk]) / ss[kk];
      sprops[kk][v] = svalid[v] ? expf(-0.5f * zz * zz) : 0.0f;
    }
    __syncthreads();
    if (tid < KMIX) {
      float den = 0.0f;
      for (int v = 0; v < VS; v++) den += sprops[tid][v];
      sden[tid] = den;
    }
    __syncthreads();

    if (tid < VS) {
      float w = 0.0f;
      for (int kk = 0; kk < KMIX; kk++) w += sprops[kk][tid] / sden[kk];
      w_out[(size_t)bp * VS + tid] = w;
      idx_out[(size_t)bp * VS + tid] = sidx[tid];
    }
  }
}

// ---------------------------------------------------------------------------
// attn5: one 256-thread block per bp; 4 waves x 2 heads each.
// Block 0 additionally zeroes the pv completion counters (runs before pv).
// ---------------------------------------------------------------------------
__global__ __launch_bounds__(256) void attn5_kernel(
    const float* __restrict__ x,     // [B,T,EMB]
    const float* __restrict__ qk,    // [B*TP, NQ]
    const int* __restrict__ idx_in,  // [B*TP, VS]
    const float* __restrict__ w_in,  // [B*TP, VS]
    float* __restrict__ z,           // [B*TP, NQ]
    int* __restrict__ cnt)           // [64] pv tile counters
{
  const int bp = blockIdx.x, b = bp >> 7;
  const int tid = threadIdx.x;
  const int wave = tid >> 6, lane = tid & 63;
  const int vsub = lane >> 4, dgrp = lane & 15;
  const int h0 = wave * 2, h1 = h0 + 1;

  if (bp == 0 && tid < 64) cnt[tid] = 0;

  __shared__ __align__(16) float xg[VS][260];
  __shared__ float part[HEADS][VS][5];
  __shared__ __align__(16) float sa[HEADS][VS];

  int myidx = 0; float myw = 0.0f;
  if (lane < VS) {
    myidx = idx_in[(size_t)bp * VS + lane];
    myw   = w_in[(size_t)bp * VS + lane];
  }

#pragma unroll
  for (int i = 0; i < 12; i++) {
    int v = wave * 12 + i;
    int row = __shfl(myidx, v, 64);
    float4 f = *(const float4*)(x + ((size_t)b * TT + row) * EMB + lane * 4);
    *(float4*)&xg[v][lane * 4] = f;
  }

  float4 q0[4], q1[4];
#pragma unroll
  for (int j = 0; j < 4; j++) {
    q0[j] = *(const float4*)(qk + (size_t)bp * NQ + h0 * 256 + dgrp * 16 + j * 4);
    q1[j] = *(const float4*)(qk + (size_t)bp * NQ + h1 * 256 + dgrp * 16 + j * 4);
  }
  __syncthreads();

#pragma unroll
  for (int it = 0; it < 12; it++) {
    int v = it * 4 + vsub;
    float p0 = 0.0f, p1 = 0.0f;
#pragma unroll
    for (int j = 0; j < 4; j++) {
      float4 xv = *(const float4*)&xg[v][dgrp * 16 + j * 4];
      p0 = fmaf(q0[j].x, xv.x, fmaf(q0[j].y, xv.y, fmaf(q0[j].z, xv.z, fmaf(q0[j].w, xv.w, p0))));
      p1 = fmaf(q1[j].x, xv.x, fmaf(q1[j].y, xv.y, fmaf(q1[j].z, xv.z, fmaf(q1[j].w, xv.w, p1))));
    }
    p0 += __shfl_xor(p0, 1, 64); p0 += __shfl_xor(p0, 2, 64);
    p1 += __shfl_xor(p1, 1, 64); p1 += __shfl_xor(p1, 2, 64);
    if ((dgrp & 3) == 0) {
      part[h0][v][dgrp >> 2] = p0;
      part[h1][v][dgrp >> 2] = p1;
    }
  }
  __syncthreads();

#pragma unroll
  for (int hh = 0; hh < 2; hh++) {
    const int h = h0 + hh;
    float logit = -1e30f;
    if (lane < VS) {
      logit = myw * (part[h][lane][0] + part[h][lane][1] +
                     part[h][lane][2] + part[h][lane][3]);
    }
    float mx = logit;
#pragma unroll
    for (int m = 32; m >= 1; m >>= 1) mx = fmaxf(mx, __shfl_xor(mx, m, 64));
    float e = (lane < VS) ? __expf(logit - mx) : 0.0f;
    float s = e;
#pragma unroll
    for (int m = 32; m >= 1; m >>= 1) s += __shfl_xor(s, m, 64);
    if (lane < VS) sa[h][lane] = e / s;
  }
  __syncthreads();

  float4 a0 = make_float4(0.f, 0.f, 0.f, 0.f);
  float4 a1 = make_float4(0.f, 0.f, 0.f, 0.f);
#pragma unroll
  for (int v0 = 0; v0 < VS; v0 += 4) {
    float4 at0 = *(const float4*)&sa[h0][v0];
    float4 at1 = *(const float4*)&sa[h1][v0];
#pragma unroll
    for (int k = 0; k < 4; k++) {
      float4 xv = *(const float4*)&xg[v0 + k][lane * 4];
      float c0 = (k == 0) ? at0.x : (k == 1) ? at0.y : (k == 2) ? at0.z : at0.w;
      float c1 = (k == 0) ? at1.x : (k == 1) ? at1.y : (k == 2) ? at1.z : at1.w;
      a0.x = fmaf(c0, xv.x, a0.x); a0.y = fmaf(c0, xv.y, a0.y);
      a0.z = fmaf(c0, xv.z, a0.z); a0.w = fmaf(c0, xv.w, a0.w);
      a1.x = fmaf(c1, xv.x, a1.x); a1.y = fmaf(c1, xv.y, a1.y);
      a1.z = fmaf(c1, xv.z, a1.z); a1.w = fmaf(c1, xv.w, a1.w);
    }
  }
  *(float4*)(z + (size_t)bp * NQ + h0 * 256 + lane * 4) = a0;
  *(float4*)(z + (size_t)bp * NQ + h1 * 256 + lane * 4) = a1;
}

// ---------------------------------------------------------------------------
// pv_fused: part_h = z_h @ PV_h (plain stores); the 8th-arriving block per
// (m,n) tile reduces all heads + bias into the sel rows of out.
// grid = (4, 16, 8). Counters pre-zeroed by attn5.
// ---------------------------------------------------------------------------
__global__ __launch_bounds__(256) void pv_fused(
    const float* __restrict__ z,    // [512, NQ]
    const float* __restrict__ PV,   // [8][256][256]
    const float* __restrict__ bu,
    float* __restrict__ part,       // [8][512][256]
    int* __restrict__ cnt,          // [64]
    float* __restrict__ out)        // [B, T, EMB]
{
  const int h = blockIdx.z;
  const float* A = z + h * 256;
  const float* W = PV + (size_t)h * EMB * EMB;
  float* C = part + (size_t)h * (BB * TP) * EMB;
  const int tid = threadIdx.x;
  const int tx = tid & 15, ty = tid >> 4;
  const int n0 = blockIdx.x * 64, m0 = blockIdx.y * 32;

  __shared__ float As[32][33];
  __shared__ __align__(16) float Bs[32][64];
  __shared__ int isLast;

  float acc[2][4];
#pragma unroll
  for (int i = 0; i < 2; i++)
#pragma unroll
    for (int j = 0; j < 4; j++) acc[i][j] = 0.0f;

  for (int k0 = 0; k0 < EMB; k0 += 32) {
    {
      int r = tid >> 3, kq = tid & 7;
      float4 v = *(const float4*)(A + (size_t)(m0 + r) * NQ + k0 + kq * 4);
      As[r][kq * 4 + 0] = v.x; As[r][kq * 4 + 1] = v.y;
      As[r][kq * 4 + 2] = v.z; As[r][kq * 4 + 3] = v.w;
    }
#pragma unroll
    for (int rr = 0; rr < 2; rr++) {
      int c = tid * 2 + rr;
      int kk = c >> 4, n4 = c & 15;
      *(float4*)(&Bs[kk][n4 * 4]) =
          *(const float4*)(W + (size_t)(k0 + kk) * EMB + n0 + n4 * 4);
    }
    __syncthreads();
#pragma unroll
    for (int kk = 0; kk < 32; kk++) {
      float a0 = As[ty * 2 + 0][kk];
      float a1 = As[ty * 2 + 1][kk];
      float4 b4 = *(const float4*)&Bs[kk][tx * 4];
      acc[0][0] = fmaf(a0, b4.x, acc[0][0]);
      acc[0][1] = fmaf(a0, b4.y, acc[0][1]);
      acc[0][2] = fmaf(a0, b4.z, acc[0][2]);
      acc[0][3] = fmaf(a0, b4.w, acc[0][3]);
      acc[1][0] = fmaf(a1, b4.x, acc[1][0]);
      acc[1][1] = fmaf(a1, b4.y, acc[1][1]);
      acc[1][2] = fmaf(a1, b4.z, acc[1][2]);
      acc[1][3] = fmaf(a1, b4.w, acc[1][3]);
    }
    __syncthreads();
  }

#pragma unroll
  for (int i = 0; i < 2; i++) {
    float* cp = C + (size_t)(m0 + ty * 2 + i) * EMB + n0 + tx * 4;
    *(float4*)cp = make_float4(acc[i][0], acc[i][1], acc[i][2], acc[i][3]);
  }

  // completion counting: 8th arrival reduces this (m,n) tile into out
  __threadfence();
  __syncthreads();
  if (tid == 0) {
    int old = atomicAdd(&cnt[blockIdx.y * 4 + blockIdx.x], 1);
    isLast = (old == 7);
  }
  __syncthreads();
  if (isLast) {
    __threadfence();
#pragma unroll
    for (int rep = 0; rep < 8; rep++) {
      int li = rep * 256 + tid;
      int row = li >> 6, col = li & 63;
      float s = bu[n0 + col];
#pragma unroll
      for (int h2 = 0; h2 < HEADS; h2++)
        s += part[((size_t)h2 * (BB * TP) + m0 + row) * EMB + n0 + col];
      out[selrow(m0 + row) * EMB + n0 + col] = s;
    }
  }
}

// ---------------------------------------------------------------------------
extern "C" void kernel_launch(void* const* d_in, const int* in_sizes, int n_in,
                              void* d_out, int out_size, void* d_ws, size_t ws_size,
                              hipStream_t stream) {
  const float* x  = (const float*)d_in[0];
  const float* Wq = (const float*)d_in[1];
  const float* Wk = (const float*)d_in[2];
  const float* Wv = (const float*)d_in[3];
  const float* Wu = (const float*)d_in[4];
  const float* bu = (const float*)d_in[5];
  const float* W1 = (const float*)d_in[6];
  const float* b1 = (const float*)d_in[7];
  const float* W2 = (const float*)d_in[8];
  const float* b2 = (const float*)d_in[9];
  float* out = (float*)d_out;

  // ---- workspace layout (~18 MB) ----
  char* ws = (char*)d_ws;
  size_t off = 0;
  auto alloc = [&](size_t bytes) { char* p = ws + off; off += (bytes + 255) & ~(size_t)255; return p; };
  float* hid0  = (float*)alloc((size_t)BB * TP * HID * 4);         // 2 MB
  float* M8    = (float*)alloc((size_t)HEADS * EMB * EMB * 4);     // 2 MB
  float* PV    = (float*)alloc((size_t)HEADS * EMB * EMB * 4);     // 2 MB
  float* qk    = (float*)alloc((size_t)BB * TP * NQ * 4);          // 4 MB
  float* zbuf  = (float*)alloc((size_t)BB * TP * NQ * 4);          // 4 MB
  float* part  = (float*)alloc((size_t)HEADS * BB * TP * EMB * 4); // 4 MB
  int*   idxb  = (int*)  alloc((size_t)BB * TP * VS * 4);
  float* wts   = (float*)alloc((size_t)BB * TP * VS * 4);
  int*   cnt   = (int*)  alloc(64 * 4);

  // L1: weight precompute (M8, PV) + MLP hidden + bu background fill
  mega1_kernel<<<dim3(768 + (BB * TT * EMB / 4) / 256), dim3(256), 0, stream>>>(
      Wq, Wk, Wv, Wu, x, W1, bu, M8, PV, hid0, out);

  // L2: params (inline RNG) + qk GEMM
  phase2_kernel<<<dim3(1024), dim3(256), 0, stream>>>(
      x, M8, hid0, W1, b1, W2, b2, qk, idxb, wts);

  // L3: fused attention (+ zero pv counters)
  attn5_kernel<<<dim3(BB * TP), dim3(256), 0, stream>>>(
      x, qk, idxb, wts, zbuf, cnt);

  // L4: part_h = z_h @ PV_h, last block per tile reduces + writes out[sel]
  pv_fused<<<dim3(EMB / 64, (BB * TP) / 32, HEADS), dim3(256), 0, stream>>>(
      zbuf, PV, bu, part, cnt, out);
}

// Round 14
// 71.788 us; speedup vs baseline: 1.6690x; 1.6690x over previous
//
#include <hip/hip_runtime.h>
#include <stdint.h>

// ---------------------------------------------------------------------------
// Problem constants (from reference)
// ---------------------------------------------------------------------------
#define EMB   256
#define HEADS 8
#define KMIX  8
#define GADD  2
#define RADD  2
#define REGION 64
#define STRIDE 32
#define BB    4
#define TT    4096
#define TP    128
#define VS    48
#define HID   1024
#define NQ    2048

// ---------------------------------------------------------------------------
// Threefry-2x32 (JAX exact, partitionable mode)
// ---------------------------------------------------------------------------
__device__ __forceinline__ uint32_t rotl32(uint32_t x, int d) {
  return (x << d) | (x >> (32 - d));
}
__device__ __forceinline__ void tf2x32(uint32_t k0, uint32_t k1,
                                       uint32_t x0, uint32_t x1,
                                       uint32_t& o0, uint32_t& o1) {
  uint32_t ks2 = k0 ^ k1 ^ 0x1BD11BDAu;
  x0 += k0; x1 += k1;
#define TFR(r) { x0 += x1; x1 = rotl32(x1, r); x1 ^= x0; }
  TFR(13) TFR(15) TFR(26) TFR(6)
  x0 += k1; x1 += ks2 + 1u;
  TFR(17) TFR(29) TFR(16) TFR(24)
  x0 += ks2; x1 += k0 + 2u;
  TFR(13) TFR(15) TFR(26) TFR(6)
  x0 += k0; x1 += k1 + 3u;
  TFR(17) TFR(29) TFR(16) TFR(24)
  x0 += k1; x1 += ks2 + 4u;
  TFR(13) TFR(15) TFR(26) TFR(6)
  x0 += ks2; x1 += k0 + 5u;
#undef TFR
  o0 = x0; o1 = x1;
}

// sel-row mapping: logical row m (0..511) -> x row index (b*TT + t)
__device__ __forceinline__ size_t selrow(int m) {
  return (size_t)(m >> 7) * TT + ((m & 127) * STRIDE + STRIDE - 1);
}

// ---------------------------------------------------------------------------
// mega1: flat grid, 4864 blocks.
//   bid <  512 : wpre  (zz<8: M8_h = Wq_h Wk_h^T / 16, NT; else PV_h = Wv_h Wu_h, NN)
//   512..767   : MLP hidden = x[sel] @ W1
//   768..4863  : fill out with bu + warm x into L3 (for attn's gather)
// ---------------------------------------------------------------------------
__global__ __launch_bounds__(256) void mega1_kernel(
    const float* __restrict__ Wq, const float* __restrict__ Wk,
    const float* __restrict__ Wv, const float* __restrict__ Wu,
    const float* __restrict__ x,  const float* __restrict__ W1,
    const float* __restrict__ bu,
    float* __restrict__ M8, float* __restrict__ PV, float* __restrict__ hid0,
    float* __restrict__ out)
{
  const int bid = blockIdx.x;
  const int tid = threadIdx.x;

  if (bid >= 768) {
    int i4 = (bid - 768) * 256 + tid;
    // warm x into L3 (keep load live; costs one float4 read overlapped w/ fill)
    float4 xw = ((const float4*)x)[i4];
    asm volatile("" :: "v"(xw.x), "v"(xw.y), "v"(xw.z), "v"(xw.w));
    ((float4*)out)[i4] = ((const float4*)bu)[i4 & 63];
    return;
  }

  const int tx = tid & 15, ty = tid >> 4;
  __shared__ float As[32][33];
  __shared__ __align__(16) float Braw[64 * 33];

  float acc[2][4];
#pragma unroll
  for (int i = 0; i < 2; i++)
#pragma unroll
    for (int j = 0; j < 4; j++) acc[i][j] = 0.0f;

  if (bid < 512) {
    const int zz = bid >> 5, rem = bid & 31;
    const int n0 = (rem & 3) * 64, m0 = (rem >> 2) * 32;
    if (zz < HEADS) {
      // NT: A = Wq_h (lda NQ), B = Wk_h (ldb NQ), C = M8_h, scale 1/16
      const float* A = Wq + zz * 256;
      const float* B = Wk + zz * 256;
      float* C = M8 + (size_t)zz * EMB * EMB;
      for (int k0 = 0; k0 < EMB; k0 += 32) {
        {
          int r = tid >> 3, kq = tid & 7;
          float4 v = *(const float4*)(A + (size_t)(m0 + r) * NQ + k0 + kq * 4);
          As[r][kq * 4 + 0] = v.x; As[r][kq * 4 + 1] = v.y;
          As[r][kq * 4 + 2] = v.z; As[r][kq * 4 + 3] = v.w;
        }
#pragma unroll
        for (int rr = 0; rr < 2; rr++) {
          int c = tid * 2 + rr;
          int r = c >> 3, kq = c & 7;
          float4 v = *(const float4*)(B + (size_t)(n0 + r) * NQ + k0 + kq * 4);
          Braw[r * 33 + kq * 4 + 0] = v.x; Braw[r * 33 + kq * 4 + 1] = v.y;
          Braw[r * 33 + kq * 4 + 2] = v.z; Braw[r * 33 + kq * 4 + 3] = v.w;
        }
        __syncthreads();
#pragma unroll
        for (int kk = 0; kk < 32; kk++) {
          float a0 = As[ty * 2 + 0][kk], a1 = As[ty * 2 + 1][kk];
          float b0 = Braw[(tx * 4 + 0) * 33 + kk];
          float b1 = Braw[(tx * 4 + 1) * 33 + kk];
          float b2 = Braw[(tx * 4 + 2) * 33 + kk];
          float b3 = Braw[(tx * 4 + 3) * 33 + kk];
          acc[0][0] = fmaf(a0, b0, acc[0][0]); acc[0][1] = fmaf(a0, b1, acc[0][1]);
          acc[0][2] = fmaf(a0, b2, acc[0][2]); acc[0][3] = fmaf(a0, b3, acc[0][3]);
          acc[1][0] = fmaf(a1, b0, acc[1][0]); acc[1][1] = fmaf(a1, b1, acc[1][1]);
          acc[1][2] = fmaf(a1, b2, acc[1][2]); acc[1][3] = fmaf(a1, b3, acc[1][3]);
        }
        __syncthreads();
      }
#pragma unroll
      for (int i = 0; i < 2; i++) {
        float* cp = C + (size_t)(m0 + ty * 2 + i) * EMB + n0 + tx * 4;
        *(float4*)cp = make_float4(acc[i][0] * 0.0625f, acc[i][1] * 0.0625f,
                                   acc[i][2] * 0.0625f, acc[i][3] * 0.0625f);
      }
    } else {
      // NN: A = Wv_h (lda NQ), W = Wu_h (ldw EMB), C = PV_h
      const int hh = zz - HEADS;
      const float* A = Wv + hh * 256;
      const float* W = Wu + (size_t)hh * 256 * EMB;
      float* C = PV + (size_t)hh * EMB * EMB;
      for (int k0 = 0; k0 < EMB; k0 += 32) {
        {
          int r = tid >> 3, kq = tid & 7;
          float4 v = *(const float4*)(A + (size_t)(m0 + r) * NQ + k0 + kq * 4);
          As[r][kq * 4 + 0] = v.x; As[r][kq * 4 + 1] = v.y;
          As[r][kq * 4 + 2] = v.z; As[r][kq * 4 + 3] = v.w;
        }
#pragma unroll
        for (int rr = 0; rr < 2; rr++) {
          int c = tid * 2 + rr;
          int kk = c >> 4, n4 = c & 15;
          *(float4*)(&Braw[kk * 64 + n4 * 4]) =
              *(const float4*)(W + (size_t)(k0 + kk) * EMB + n0 + n4 * 4);
        }
        __syncthreads();
#pragma unroll
        for (int kk = 0; kk < 32; kk++) {
          float a0 = As[ty * 2 + 0][kk], a1 = As[ty * 2 + 1][kk];
          float4 b4 = *(const float4*)&Braw[kk * 64 + tx * 4];
          acc[0][0] = fmaf(a0, b4.x, acc[0][0]); acc[0][1] = fmaf(a0, b4.y, acc[0][1]);
          acc[0][2] = fmaf(a0, b4.z, acc[0][2]); acc[0][3] = fmaf(a0, b4.w, acc[0][3]);
          acc[1][0] = fmaf(a1, b4.x, acc[1][0]); acc[1][1] = fmaf(a1, b4.y, acc[1][1]);
          acc[1][2] = fmaf(a1, b4.z, acc[1][2]); acc[1][3] = fmaf(a1, b4.w, acc[1][3]);
        }
        __syncthreads();
      }
#pragma unroll
      for (int i = 0; i < 2; i++) {
        float* cp = C + (size_t)(m0 + ty * 2 + i) * EMB + n0 + tx * 4;
        *(float4*)cp = make_float4(acc[i][0], acc[i][1], acc[i][2], acc[i][3]);
      }
    }
  } else {
    // MLP hidden: A = sel rows of x, W = W1 (ldw HID), C = hid0
    const int idx = bid - 512;
    const int n0 = (idx & 15) * 64, m0 = (idx >> 4) * 32;
    for (int k0 = 0; k0 < EMB; k0 += 32) {
      {
        int r = tid >> 3, kq = tid & 7;
        float4 v = *(const float4*)(x + selrow(m0 + r) * EMB + k0 + kq * 4);
        As[r][kq * 4 + 0] = v.x; As[r][kq * 4 + 1] = v.y;
        As[r][kq * 4 + 2] = v.z; As[r][kq * 4 + 3] = v.w;
      }
#pragma unroll
      for (int rr = 0; rr < 2; rr++) {
        int c = tid * 2 + rr;
        int kk = c >> 4, n4 = c & 15;
        *(float4*)(&Braw[kk * 64 + n4 * 4]) =
            *(const float4*)(W1 + (size_t)(k0 + kk) * HID + n0 + n4 * 4);
      }
      __syncthreads();
#pragma unroll
      for (int kk = 0; kk < 32; kk++) {
        float a0 = As[ty * 2 + 0][kk], a1 = As[ty * 2 + 1][kk];
        float4 b4 = *(const float4*)&Braw[kk * 64 + tx * 4];
        acc[0][0] = fmaf(a0, b4.x, acc[0][0]); acc[0][1] = fmaf(a0, b4.y, acc[0][1]);
        acc[0][2] = fmaf(a0, b4.z, acc[0][2]); acc[0][3] = fmaf(a0, b4.w, acc[0][3]);
        acc[1][0] = fmaf(a1, b4.x, acc[1][0]); acc[1][1] = fmaf(a1, b4.y, acc[1][1]);
        acc[1][2] = fmaf(a1, b4.z, acc[1][2]); acc[1][3] = fmaf(a1, b4.w, acc[1][3]);
      }
      __syncthreads();
    }
#pragma unroll
    for (int i = 0; i < 2; i++) {
      float* cp = hid0 + (size_t)(m0 + ty * 2 + i) * HID + n0 + tx * 4;
      *(float4*)cp = make_float4(acc[i][0], acc[i][1], acc[i][2], acc[i][3]);
    }
  }
}

// ---------------------------------------------------------------------------
__device__ __forceinline__ float softplus_f(float v) {
  return fmaxf(v, 0.0f) + log1pf(expf(-fabsf(v)));
}

// ---------------------------------------------------------------------------
// phase2: flat grid. bid<512: qk GEMM (qk_h = x[sel] @ M_h).
// bid>=512: params (MLP finish + indices/weights, inline RNG).
// ---------------------------------------------------------------------------
__global__ __launch_bounds__(256) void phase2_kernel(
    const float* __restrict__ x,  const float* __restrict__ M8,
    const float* __restrict__ hid0,
    const float* __restrict__ W1, const float* __restrict__ b1,
    const float* __restrict__ W2, const float* __restrict__ b2,
    float* __restrict__ qk, int* __restrict__ idx_out, float* __restrict__ w_out)
{
  const int bid = blockIdx.x;
  const int tid = threadIdx.x;

  if (bid < 512) {
    const int h = bid >> 6, rem = bid & 63;
    const int n0 = (rem & 3) * 64, m0 = (rem >> 2) * 32;
    const int tx = tid & 15, ty = tid >> 4;
    const float* W = M8 + (size_t)h * EMB * EMB;

    __shared__ float As[32][33];
    __shared__ __align__(16) float Bs[32][64];

    float acc[2][4];
#pragma unroll
    for (int i = 0; i < 2; i++)
#pragma unroll
      for (int j = 0; j < 4; j++) acc[i][j] = 0.0f;

    for (int k0 = 0; k0 < EMB; k0 += 32) {
      {
        int r = tid >> 3, kq = tid & 7;
        float4 v = *(const float4*)(x + selrow(m0 + r) * EMB + k0 + kq * 4);
        As[r][kq * 4 + 0] = v.x; As[r][kq * 4 + 1] = v.y;
        As[r][kq * 4 + 2] = v.z; As[r][kq * 4 + 3] = v.w;
      }
#pragma unroll
      for (int rr = 0; rr < 2; rr++) {
        int c = tid * 2 + rr;
        int kk = c >> 4, n4 = c & 15;
        *(float4*)(&Bs[kk][n4 * 4]) =
            *(const float4*)(W + (size_t)(k0 + kk) * EMB + n0 + n4 * 4);
      }
      __syncthreads();
#pragma unroll
      for (int kk = 0; kk < 32; kk++) {
        float a0 = As[ty * 2 + 0][kk], a1 = As[ty * 2 + 1][kk];
        float4 b4 = *(const float4*)&Bs[kk][tx * 4];
        acc[0][0] = fmaf(a0, b4.x, acc[0][0]); acc[0][1] = fmaf(a0, b4.y, acc[0][1]);
        acc[0][2] = fmaf(a0, b4.z, acc[0][2]); acc[0][3] = fmaf(a0, b4.w, acc[0][3]);
        acc[1][0] = fmaf(a1, b4.x, acc[1][0]); acc[1][1] = fmaf(a1, b4.y, acc[1][1]);
        acc[1][2] = fmaf(a1, b4.z, acc[1][2]); acc[1][3] = fmaf(a1, b4.w, acc[1][3]);
      }
      __syncthreads();
    }
#pragma unroll
    for (int i = 0; i < 2; i++) {
      float* cp = qk + (size_t)(m0 + ty * 2 + i) * NQ + h * 256 + n0 + tx * 4;
      *(float4*)cp = make_float4(acc[i][0], acc[i][1], acc[i][2], acc[i][3]);
    }
  } else {
    const int bp = bid - 512;
    const int b = bp >> 7, p = bp & 127;
    const int selp = STRIDE * p + STRIDE - 1;
    const float coordp = (float)p / (float)TP;
    (void)b;

    __shared__ float shid[HID];
    __shared__ float spartial[256];
    __shared__ float spar[2 * KMIX];
    __shared__ float sm[KMIX], ss[KMIX];
    __shared__ int   sidx[VS];
    __shared__ float sidxf[VS];
    __shared__ int   svalid[VS];
    __shared__ float sprops[KMIX][VS];
    __shared__ float sden[KMIX];
    __shared__ int   sgrand[16], srrand[16];

    if (tid < 16) {
      uint32_t i = (uint32_t)(bp * 16 + tid);
      uint32_t kg0, kg1, kr0, kr1, g2k0, g2k1, r2k0, r2k1, o0, o1;
      tf2x32(0u, 42u, 0u, 0u, kg0, kg1);
      tf2x32(0u, 42u, 0u, 1u, kr0, kr1);
      tf2x32(kg0, kg1, 0u, 1u, g2k0, g2k1);
      tf2x32(kr0, kr1, 0u, 1u, r2k0, r2k1);
      tf2x32(g2k0, g2k1, 0u, i, o0, o1);
      sgrand[tid] = (int)((o0 ^ o1) & 4095u);
      tf2x32(r2k0, r2k1, 0u, i, o0, o1);
      srrand[tid] = (int)((o0 ^ o1) & 63u);
    }

#pragma unroll
    for (int q = 0; q < HID / 256; q++) {
      int j = q * 256 + tid;
      shid[j] = fmaxf(hid0[(size_t)bp * HID + j] + coordp * W1[(size_t)EMB * HID + j] + b1[j], 0.0f);
    }
    __syncthreads();

    {
      int o = tid & 15, g = tid >> 4;
      float pa = 0.0f;
      for (int jj = 0; jj < 64; jj++) {
        int j = g * 64 + jj;
        pa = fmaf(shid[j], W2[j * (2 * KMIX) + o], pa);
      }
      spartial[o * 16 + g] = pa;
    }
    __syncthreads();
    if (tid < 2 * KMIX) {
      float acc = 0.0f;
      for (int g = 0; g < 16; g++) acc += spartial[tid * 16 + g];
      spar[tid] = acc + b2[tid];
    }
    __syncthreads();

    if (tid < KMIX) {
      float m = (float)selp - 3.0f * softplus_f(spar[tid]);
      m = fminf(fmaxf(m, 0.0f), (float)(TT - 1));
      sm[tid] = m;
      ss[tid] = (softplus_f(spar[KMIX + tid] + 2.0f) + 0.05f) * (float)TT * 0.1f;
    }
    __syncthreads();

    if (tid < VS) {
      int kk = tid / 6, jj = tid % 6;
      float fl = floorf(sm[kk]);
      float v;
      if (jj == 0) v = fl;
      else if (jj == 1) v = fl + 1.0f;
      else if (jj < 4) v = (float)sgrand[kk * GADD + (jj - 2)];
      else {
        float lo = fminf(fmaxf(fl - (float)(REGION / 2), 0.0f), (float)(TT - REGION));
        v = lo + (float)srrand[kk * RADD + (jj - 4)];
      }
      v = fminf(fmaxf(v, 0.0f), (float)(TT - 1));
      int ii = (int)v;
      sidx[tid] = ii;
      sidxf[tid] = (float)ii;
    }
    __syncthreads();

    if (tid < VS) {
      int d = 0;
      for (int u = 0; u < tid; u++) d |= (sidx[u] == sidx[tid]);
      svalid[tid] = (!d) && (sidx[tid] <= selp);
    }
    __syncthreads();

    for (int l = tid; l < KMIX * VS; l += 256) {
      int kk = l / VS, v = l - kk * VS;
      float zz = (sidxf[v] - sm[kk]) / ss[kk];
      sprops[kk][v] = svalid[v] ? expf(-0.5f * zz * zz) : 0.0f;
    }
    __syncthreads();
    if (tid < KMIX) {
      float den = 0.0f;
      for (int v = 0; v < VS; v++) den += sprops[tid][v];
      sden[tid] = den;
    }
    __syncthreads();

    if (tid < VS) {
      float w = 0.0f;
      for (int kk = 0; kk < KMIX; kk++) w += sprops[kk][tid] / sden[kk];
      w_out[(size_t)bp * VS + tid] = w;
      idx_out[(size_t)bp * VS + tid] = sidx[tid];
    }
  }
}

// ---------------------------------------------------------------------------
// attn5: one 256-thread block per bp; 4 waves x 2 heads each.
// ---------------------------------------------------------------------------
__global__ __launch_bounds__(256) void attn5_kernel(
    const float* __restrict__ x,     // [B,T,EMB]
    const float* __restrict__ qk,    // [B*TP, NQ]
    const int* __restrict__ idx_in,  // [B*TP, VS]
    const float* __restrict__ w_in,  // [B*TP, VS]
    float* __restrict__ z)           // [B*TP, NQ]
{
  const int bp = blockIdx.x, b = bp >> 7;
  const int tid = threadIdx.x;
  const int wave = tid >> 6, lane = tid & 63;
  const int vsub = lane >> 4, dgrp = lane & 15;
  const int h0 = wave * 2, h1 = h0 + 1;

  __shared__ __align__(16) float xg[VS][260];
  __shared__ float part[HEADS][VS][5];
  __shared__ __align__(16) float sa[HEADS][VS];

  int myidx = 0; float myw = 0.0f;
  if (lane < VS) {
    myidx = idx_in[(size_t)bp * VS + lane];
    myw   = w_in[(size_t)bp * VS + lane];
  }

#pragma unroll
  for (int i = 0; i < 12; i++) {
    int v = wave * 12 + i;
    int row = __shfl(myidx, v, 64);
    float4 f = *(const float4*)(x + ((size_t)b * TT + row) * EMB + lane * 4);
    *(float4*)&xg[v][lane * 4] = f;
  }

  float4 q0[4], q1[4];
#pragma unroll
  for (int j = 0; j < 4; j++) {
    q0[j] = *(const float4*)(qk + (size_t)bp * NQ + h0 * 256 + dgrp * 16 + j * 4);
    q1[j] = *(const float4*)(qk + (size_t)bp * NQ + h1 * 256 + dgrp * 16 + j * 4);
  }
  __syncthreads();

#pragma unroll
  for (int it = 0; it < 12; it++) {
    int v = it * 4 + vsub;
    float p0 = 0.0f, p1 = 0.0f;
#pragma unroll
    for (int j = 0; j < 4; j++) {
      float4 xv = *(const float4*)&xg[v][dgrp * 16 + j * 4];
      p0 = fmaf(q0[j].x, xv.x, fmaf(q0[j].y, xv.y, fmaf(q0[j].z, xv.z, fmaf(q0[j].w, xv.w, p0))));
      p1 = fmaf(q1[j].x, xv.x, fmaf(q1[j].y, xv.y, fmaf(q1[j].z, xv.z, fmaf(q1[j].w, xv.w, p1))));
    }
    p0 += __shfl_xor(p0, 1, 64); p0 += __shfl_xor(p0, 2, 64);
    p1 += __shfl_xor(p1, 1, 64); p1 += __shfl_xor(p1, 2, 64);
    if ((dgrp & 3) == 0) {
      part[h0][v][dgrp >> 2] = p0;
      part[h1][v][dgrp >> 2] = p1;
    }
  }
  __syncthreads();

#pragma unroll
  for (int hh = 0; hh < 2; hh++) {
    const int h = h0 + hh;
    float logit = -1e30f;
    if (lane < VS) {
      logit = myw * (part[h][lane][0] + part[h][lane][1] +
                     part[h][lane][2] + part[h][lane][3]);
    }
    float mx = logit;
#pragma unroll
    for (int m = 32; m >= 1; m >>= 1) mx = fmaxf(mx, __shfl_xor(mx, m, 64));
    float e = (lane < VS) ? __expf(logit - mx) : 0.0f;
    float s = e;
#pragma unroll
    for (int m = 32; m >= 1; m >>= 1) s += __shfl_xor(s, m, 64);
    if (lane < VS) sa[h][lane] = e / s;
  }
  __syncthreads();

  float4 a0 = make_float4(0.f, 0.f, 0.f, 0.f);
  float4 a1 = make_float4(0.f, 0.f, 0.f, 0.f);
#pragma unroll
  for (int v0 = 0; v0 < VS; v0 += 4) {
    float4 at0 = *(const float4*)&sa[h0][v0];
    float4 at1 = *(const float4*)&sa[h1][v0];
#pragma unroll
    for (int k = 0; k < 4; k++) {
      float4 xv = *(const float4*)&xg[v0 + k][lane * 4];
      float c0 = (k == 0) ? at0.x : (k == 1) ? at0.y : (k == 2) ? at0.z : at0.w;
      float c1 = (k == 0) ? at1.x : (k == 1) ? at1.y : (k == 2) ? at1.z : at1.w;
      a0.x = fmaf(c0, xv.x, a0.x); a0.y = fmaf(c0, xv.y, a0.y);
      a0.z = fmaf(c0, xv.z, a0.z); a0.w = fmaf(c0, xv.w, a0.w);
      a1.x = fmaf(c1, xv.x, a1.x); a1.y = fmaf(c1, xv.y, a1.y);
      a1.z = fmaf(c1, xv.z, a1.z); a1.w = fmaf(c1, xv.w, a1.w);
    }
  }
  *(float4*)(z + (size_t)bp * NQ + h0 * 256 + lane * 4) = a0;
  *(float4*)(z + (size_t)bp * NQ + h1 * 256 + lane * 4) = a1;
}

// ---------------------------------------------------------------------------
// pv_gemm: part_h = z_h @ PV_h (batched over heads, plain stores).
// Tile 32x64, BK=32. grid = (4, 16, 8).
// ---------------------------------------------------------------------------
__global__ __launch_bounds__(256) void pv_gemm(
    const float* __restrict__ z,    // [512, NQ]
    const float* __restrict__ PV,   // [8][256][256]
    float* __restrict__ part)       // [8][512][256]
{
  const int h = blockIdx.z;
  const float* A = z + h * 256;
  const float* W = PV + (size_t)h * EMB * EMB;
  float* C = part + (size_t)h * (BB * TP) * EMB;
  const int tid = threadIdx.x;
  const int tx = tid & 15, ty = tid >> 4;
  const int n0 = blockIdx.x * 64, m0 = blockIdx.y * 32;

  __shared__ float As[32][33];
  __shared__ __align__(16) float Bs[32][64];

  float acc[2][4];
#pragma unroll
  for (int i = 0; i < 2; i++)
#pragma unroll
    for (int j = 0; j < 4; j++) acc[i][j] = 0.0f;

  for (int k0 = 0; k0 < EMB; k0 += 32) {
    {
      int r = tid >> 3, kq = tid & 7;
      float4 v = *(const float4*)(A + (size_t)(m0 + r) * NQ + k0 + kq * 4);
      As[r][kq * 4 + 0] = v.x; As[r][kq * 4 + 1] = v.y;
      As[r][kq * 4 + 2] = v.z; As[r][kq * 4 + 3] = v.w;
    }
#pragma unroll
    for (int rr = 0; rr < 2; rr++) {
      int c = tid * 2 + rr;
      int kk = c >> 4, n4 = c & 15;
      *(float4*)(&Bs[kk][n4 * 4]) =
          *(const float4*)(W + (size_t)(k0 + kk) * EMB + n0 + n4 * 4);
    }
    __syncthreads();
#pragma unroll
    for (int kk = 0; kk < 32; kk++) {
      float a0 = As[ty * 2 + 0][kk];
      float a1 = As[ty * 2 + 1][kk];
      float4 b4 = *(const float4*)&Bs[kk][tx * 4];
      acc[0][0] = fmaf(a0, b4.x, acc[0][0]);
      acc[0][1] = fmaf(a0, b4.y, acc[0][1]);
      acc[0][2] = fmaf(a0, b4.z, acc[0][2]);
      acc[0][3] = fmaf(a0, b4.w, acc[0][3]);
      acc[1][0] = fmaf(a1, b4.x, acc[1][0]);
      acc[1][1] = fmaf(a1, b4.y, acc[1][1]);
      acc[1][2] = fmaf(a1, b4.z, acc[1][2]);
      acc[1][3] = fmaf(a1, b4.w, acc[1][3]);
    }
    __syncthreads();
  }

#pragma unroll
  for (int i = 0; i < 2; i++) {
    float* cp = C + (size_t)(m0 + ty * 2 + i) * EMB + n0 + tx * 4;
    *(float4*)cp = make_float4(acc[i][0], acc[i][1], acc[i][2], acc[i][3]);
  }
}

// ---------------------------------------------------------------------------
// sel_reduce: out[sel bp] = bu + sum_h part[h][bp]  (512 blocks only)
// ---------------------------------------------------------------------------
__global__ __launch_bounds__(256) void sel_reduce(
    const float* __restrict__ part,  // [8][512][256]
    const float* __restrict__ bu,
    float* __restrict__ out)
{
  const int bp = blockIdx.x, e = threadIdx.x;
  float s = bu[e];
#pragma unroll
  for (int h = 0; h < HEADS; h++)
    s += part[((size_t)h * (BB * TP) + bp) * EMB + e];
  out[selrow(bp) * EMB + e] = s;
}

// ---------------------------------------------------------------------------
extern "C" void kernel_launch(void* const* d_in, const int* in_sizes, int n_in,
                              void* d_out, int out_size, void* d_ws, size_t ws_size,
                              hipStream_t stream) {
  const float* x  = (const float*)d_in[0];
  const float* Wq = (const float*)d_in[1];
  const float* Wk = (const float*)d_in[2];
  const float* Wv = (const float*)d_in[3];
  const float* Wu = (const float*)d_in[4];
  const float* bu = (const float*)d_in[5];
  const float* W1 = (const float*)d_in[6];
  const float* b1 = (const float*)d_in[7];
  const float* W2 = (const float*)d_in[8];
  const float* b2 = (const float*)d_in[9];
  float* out = (float*)d_out;

  // ---- workspace layout (~18 MB) ----
  char* ws = (char*)d_ws;
  size_t off = 0;
  auto alloc = [&](size_t bytes) { char* p = ws + off; off += (bytes + 255) & ~(size_t)255; return p; };
  float* hid0  = (float*)alloc((size_t)BB * TP * HID * 4);         // 2 MB
  float* M8    = (float*)alloc((size_t)HEADS * EMB * EMB * 4);     // 2 MB
  float* PV    = (float*)alloc((size_t)HEADS * EMB * EMB * 4);     // 2 MB
  float* qk    = (float*)alloc((size_t)BB * TP * NQ * 4);          // 4 MB
  float* zbuf  = (float*)alloc((size_t)BB * TP * NQ * 4);          // 4 MB
  float* part  = (float*)alloc((size_t)HEADS * BB * TP * EMB * 4); // 4 MB
  int*   idxb  = (int*)  alloc((size_t)BB * TP * VS * 4);
  float* wts   = (float*)alloc((size_t)BB * TP * VS * 4);

  // L1: weight precompute (M8, PV) + MLP hidden + bu fill + x L3-warm
  mega1_kernel<<<dim3(768 + (BB * TT * EMB / 4) / 256), dim3(256), 0, stream>>>(
      Wq, Wk, Wv, Wu, x, W1, bu, M8, PV, hid0, out);

  // L2: params (inline RNG) + qk GEMM
  phase2_kernel<<<dim3(1024), dim3(256), 0, stream>>>(
      x, M8, hid0, W1, b1, W2, b2, qk, idxb, wts);

  // L3: fused attention
  attn5_kernel<<<dim3(BB * TP), dim3(256), 0, stream>>>(
      x, qk, idxb, wts, zbuf);

  // L4: part_h = z_h @ PV_h (plain stores)
  pv_gemm<<<dim3(EMB / 64, (BB * TP) / 32, HEADS), dim3(256), 0, stream>>>(
      zbuf, PV, part);

  // L5: out[sel] = bu + sum_h part (512 blocks)
  sel_reduce<<<dim3(BB * TP), dim3(256), 0, stream>>>(part, bu, out);
}